// Round 1
// baseline (1659.605 us; speedup 1.0000x reference)
//
#include <hip/hip_runtime.h>

// Problem constants (from reference setup_inputs)
#define NN 100000      // nodes
#define NE 600000      // edges
#define D  128         // d_in (both layers; h is [N,128])
#define DOUT2 96
#define NREL 4
#define KREL 512       // NREL * D
#define KCAT 640       // KREL + D

// ---------------------------------------------------------------------------
// Degree count: cnt[v][r] = #edges with dst=v, etype=r (float for cheap 1/x)
__global__ void count_deg(const int* __restrict__ dst,
                          const int* __restrict__ et,
                          float* __restrict__ cnt) {
    int e = blockIdx.x * blockDim.x + threadIdx.x;
    if (e < NE) unsafeAtomicAdd(&cnt[dst[e] * NREL + et[e]], 1.0f);
}

// ---------------------------------------------------------------------------
// Scatter: A[dst][etype*128 + j] += norm_e * x[src][j]
// One block (128 threads) per edge; A is [N, 512] row-major, pre-zeroed.
__global__ void scatter_edges(const float* __restrict__ x,
                              const int* __restrict__ src,
                              const int* __restrict__ dst,
                              const int* __restrict__ et,
                              const float* __restrict__ cnt,
                              float* __restrict__ A) {
    int e = blockIdx.x;
    int s = src[e], d = dst[e], t = et[e];
    float c = cnt[d * NREL + t];
    float norm = 1.0f / fmaxf(c, 1.0f);
    int j = threadIdx.x;  // 0..127
    float v = norm * x[(size_t)s * D + j];
    unsafeAtomicAdd(&A[(size_t)d * KREL + t * D + j], v);
}

// ---------------------------------------------------------------------------
// Wcat[0:512, :] = W (R*D rows, already contiguous); Wcat[512:640, :] = root
__global__ void build_wcat(const float* __restrict__ W,
                           const float* __restrict__ root,
                           float* __restrict__ Wcat, int nout) {
    int i = blockIdx.x * blockDim.x + threadIdx.x;
    int total = KCAT * nout;
    if (i >= total) return;
    int relpart = KREL * nout;
    Wcat[i] = (i < relpart) ? W[i] : root[i - relpart];
}

// ---------------------------------------------------------------------------
// C[M, Nout] = concat([A (M x 512), X (M x 128)], axis=1) @ B (640 x Nout)
//              + bias, optional ReLU.
// fp32 register-tiled: BM=64, BK=16, block 256 threads, thread tile 4 x CN.
// BN == Nout (grid.y == 1). Layer1: BN=128,CN=8; Layer2: BN=96,CN=6.
template <int BN, int CN, bool RELU>
__global__ __launch_bounds__(256) void gemm_cat(
    const float* __restrict__ A,    // [M, 512]
    const float* __restrict__ X,    // [M, 128]
    const float* __restrict__ B,    // [640, BN]
    const float* __restrict__ bias, // [BN]
    float* __restrict__ C,          // [M, BN]
    int M) {
    constexpr int BM = 64, BK = 16;
    __shared__ float As[BK][BM + 4];  // +4 pad: 16B-aligned rows, 2-way-max bank alias
    __shared__ float Bs[BK][BN];

    const int m0 = blockIdx.x * BM;
    const int tid = threadIdx.x;
    const int tx = tid & 15;   // col group
    const int ty = tid >> 4;   // row group

    float acc[4][CN];
#pragma unroll
    for (int i = 0; i < 4; i++)
#pragma unroll
        for (int j = 0; j < CN; j++) acc[i][j] = 0.0f;

    for (int k0 = 0; k0 < KCAT; k0 += BK) {
        // Select source segment (uniform per tile; BK divides 128)
        const float* Ap;
        int lda, koff;
        if (k0 < KREL) { Ap = A; lda = KREL; koff = k0; }
        else           { Ap = X; lda = D;    koff = k0 - KREL; }

        // Stage A tile (64 rows x 16 k), transposed into As[k][m]
#pragma unroll
        for (int i = tid; i < BM * BK; i += 256) {
            int row = i >> 4, kk = i & 15;
            int m = m0 + row;
            As[kk][row] = (m < M) ? Ap[(size_t)m * lda + koff + kk] : 0.0f;
        }
        // Stage B tile (16 k x BN cols)
#pragma unroll
        for (int i = tid; i < BK * BN; i += 256) {
            int kr = i / BN, nc = i % BN;
            Bs[kr][nc] = B[(size_t)(k0 + kr) * BN + nc];
        }
        __syncthreads();

#pragma unroll
        for (int kk = 0; kk < BK; kk++) {
            float a[4], b[CN];
#pragma unroll
            for (int i = 0; i < 4; i++) a[i] = As[kk][ty * 4 + i];
#pragma unroll
            for (int j = 0; j < CN; j++) b[j] = Bs[kk][tx * CN + j];
#pragma unroll
            for (int i = 0; i < 4; i++)
#pragma unroll
                for (int j = 0; j < CN; j++) acc[i][j] += a[i] * b[j];
        }
        __syncthreads();
    }

#pragma unroll
    for (int i = 0; i < 4; i++) {
        int m = m0 + ty * 4 + i;
        if (m >= M) continue;
#pragma unroll
        for (int j = 0; j < CN; j++) {
            int n = tx * CN + j;
            float v = acc[i][j] + bias[n];
            if (RELU) v = fmaxf(v, 0.0f);
            C[(size_t)m * BN + n] = v;
        }
    }
}

// ---------------------------------------------------------------------------
extern "C" void kernel_launch(void* const* d_in, const int* in_sizes, int n_in,
                              void* d_out, int out_size, void* d_ws, size_t ws_size,
                              hipStream_t stream) {
    const float* x     = (const float*)d_in[0];
    const int*   ei    = (const int*)d_in[1];   // [2, NE]
    const int*   et    = (const int*)d_in[2];   // [NE]
    const float* W1    = (const float*)d_in[3]; // [4,128,128]
    const float* root1 = (const float*)d_in[4]; // [128,128]
    const float* b1    = (const float*)d_in[5];
    const float* W2    = (const float*)d_in[6]; // [4,128,96]
    const float* root2 = (const float*)d_in[7]; // [128,96]
    const float* b2    = (const float*)d_in[8];
    const int* srcp = ei;
    const int* dstp = ei + NE;
    float* out = (float*)d_out;

    // Workspace layout (floats). Total ~258.2 MB.
    float* A   = (float*)d_ws;                    // NN*512 = 51,200,000
    float* h   = A   + (size_t)NN * KREL;         // NN*128 = 12,800,000
    float* cnt = h   + (size_t)NN * D;            // NN*4   =    400,000
    float* Wc1 = cnt + (size_t)NN * NREL;         // 640*128=     81,920
    float* Wc2 = Wc1 + (size_t)KCAT * D;          // 640*96 =     61,440

    const int mblocks = (NN + 63) / 64;  // 1563

    // Shared preliminaries
    hipMemsetAsync(cnt, 0, (size_t)NN * NREL * sizeof(float), stream);
    count_deg<<<(NE + 255) / 256, 256, 0, stream>>>(dstp, et, cnt);
    build_wcat<<<(KCAT * D + 255) / 256, 256, 0, stream>>>(W1, root1, Wc1, D);
    build_wcat<<<(KCAT * DOUT2 + 255) / 256, 256, 0, stream>>>(W2, root2, Wc2, DOUT2);

    // ---- Layer 1: h = relu([A|x] @ Wc1 + b1) ----
    hipMemsetAsync(A, 0, (size_t)NN * KREL * sizeof(float), stream);
    scatter_edges<<<NE, D, 0, stream>>>(x, srcp, dstp, et, cnt, A);
    gemm_cat<128, 8, true><<<dim3(mblocks, 1), 256, 0, stream>>>(A, x, Wc1, b1, h, NN);

    // ---- Layer 2: out = [A|h] @ Wc2 + b2 ----
    hipMemsetAsync(A, 0, (size_t)NN * KREL * sizeof(float), stream);
    scatter_edges<<<NE, D, 0, stream>>>(h, srcp, dstp, et, cnt, A);
    gemm_cat<96, 6, false><<<dim3(mblocks, 1), 256, 0, stream>>>(A, h, Wc2, b2, out, NN);
}

// Round 2
// 1014.389 us; speedup vs baseline: 1.6361x; 1.6361x over previous
//
#include <hip/hip_runtime.h>

// Problem constants (from reference setup_inputs)
#define NN 100000      // nodes
#define NE 600000      // edges
#define D  128         // d_in (both layers; h is [N,128])
#define DOUT2 96
#define NREL 4
#define KREL 512       // NREL * D
#define KCAT 640       // KREL + D

typedef short short8 __attribute__((ext_vector_type(8)));   // 8 bf16
typedef float f32x4  __attribute__((ext_vector_type(4)));

// fp32 -> bf16, round-to-nearest-even (finite inputs)
__device__ __forceinline__ short f2bf(float x) {
    unsigned u = __builtin_bit_cast(unsigned, x);
    u += 0x7fffu + ((u >> 16) & 1u);
    return (short)(u >> 16);
}

// ---------------------------------------------------------------------------
// Degree count: cnt[v][r] = #edges with dst=v, etype=r
__global__ void count_deg(const int* __restrict__ dst,
                          const int* __restrict__ et,
                          float* __restrict__ cnt) {
    int e = blockIdx.x * blockDim.x + threadIdx.x;
    if (e < NE) unsafeAtomicAdd(&cnt[dst[e] * NREL + et[e]], 1.0f);
}

// ---------------------------------------------------------------------------
// Scatter: A[dst][etype*128 + j] += norm_e * x[src][j]
__global__ void scatter_edges(const float* __restrict__ x,
                              const int* __restrict__ src,
                              const int* __restrict__ dst,
                              const int* __restrict__ et,
                              const float* __restrict__ cnt,
                              float* __restrict__ A) {
    int e = blockIdx.x;
    int s = src[e], d = dst[e], t = et[e];
    float c = cnt[d * NREL + t];
    float norm = 1.0f / fmaxf(c, 1.0f);
    int j = threadIdx.x;  // 0..127
    float v = norm * x[(size_t)s * D + j];
    unsafeAtomicAdd(&A[(size_t)d * KREL + t * D + j], v);
}

// ---------------------------------------------------------------------------
// Pack Wcat (= [W (512 x BN); root (128 x BN)]) into bf16 MFMA-B-fragment
// order: Wcp[kq][n][j] = Wcat[kq*8+j][n], kq in [0,80), j in [0,8).
// A lane's B-fragment (8 bf16 along k) is then 16 contiguous bytes.
__global__ void pack_wcp(const float* __restrict__ W,
                         const float* __restrict__ root,
                         short* __restrict__ Wcp, int BN) {
    int i = blockIdx.x * blockDim.x + threadIdx.x;
    int total = KCAT * BN;  // 80*BN*8
    if (i >= total) return;
    int j = i & 7;
    int rest = i >> 3;
    int n = rest % BN;
    int kq = rest / BN;
    int k = kq * 8 + j;
    float v = (k < KREL) ? W[(size_t)k * BN + n] : root[(size_t)(k - KREL) * BN + n];
    Wcp[i] = f2bf(v);
}

// ---------------------------------------------------------------------------
// C[M,BN] = concat([A (M x 512) | X (M x 128)]) @ Wcat (640 x BN) + bias
// bf16 MFMA (16x16x32), fp32 accumulate. BM=64 (4 waves x 16 rows), BK=64.
// A fragments read directly from global fp32 (no reuse -> no LDS), converted
// to bf16 in-register. B staged per k-tile into LDS from pre-packed Wcp
// (contiguous copy; fragment ds_reads are conflict-free b128).
template <int BN, bool RELU>
__global__ __launch_bounds__(256) void gemm_mfma(
    const float* __restrict__ A,    // [M, 512]
    const float* __restrict__ X,    // [M, 128]
    const short* __restrict__ Wcp,  // [80][BN][8] bf16
    const float* __restrict__ bias, // [BN]
    float* __restrict__ C,          // [M, BN]
    int M) {
    constexpr int NF = BN / 16;          // 8 (layer1) or 6 (layer2)
    __shared__ short Bs[64 * BN];        // 8 kq-groups x BN x 8 bf16 (16/12 KB)

    const int tid  = threadIdx.x;
    const int wave = tid >> 6;
    const int lane = tid & 63;
    const int m16  = lane & 15;          // A row within 16 / B col within frag
    const int q    = lane >> 4;          // k-quad

    const int m0  = blockIdx.x * 64;
    const int row = m0 + wave * 16 + m16;
    const int rowc = (row < M) ? row : (M - 1);   // clamp loads, guard stores

    f32x4 acc[NF];
#pragma unroll
    for (int i = 0; i < NF; i++) acc[i] = (f32x4)0.0f;

    for (int k0 = 0; k0 < KCAT; k0 += 64) {
        // ---- stage B tile: contiguous 64*BN bf16 from Wcp[k0*BN] ----
        {
            const uint4* srcB = (const uint4*)(Wcp + (size_t)k0 * BN);
            uint4* dstB = (uint4*)Bs;
            constexpr int NV = 64 * BN / 8;   // uint4 count (1024 / 768)
#pragma unroll
            for (int i = tid; i < NV; i += 256) dstB[i] = srcB[i];
        }
        __syncthreads();

        // ---- A source segment (uniform branch) ----
        const float* rp;
        int cb;
        if (k0 < KREL) { rp = A + (size_t)rowc * KREL; cb = k0; }
        else           { rp = X + (size_t)rowc * D;    cb = k0 - KREL; }

#pragma unroll
        for (int s = 0; s < 2; s++) {     // two MFMA k-steps of 32
            const float* p = rp + cb + s * 32 + q * 8;
            float4 a0 = *(const float4*)p;
            float4 a1 = *(const float4*)(p + 4);
            short8 af;
            af[0] = f2bf(a0.x); af[1] = f2bf(a0.y);
            af[2] = f2bf(a0.z); af[3] = f2bf(a0.w);
            af[4] = f2bf(a1.x); af[5] = f2bf(a1.y);
            af[6] = f2bf(a1.z); af[7] = f2bf(a1.w);
#pragma unroll
            for (int nf = 0; nf < NF; nf++) {
                const short8* bp =
                    (const short8*)&Bs[(((s * 4 + q) * BN) + nf * 16 + m16) * 8];
                short8 bf = *bp;
                acc[nf] = __builtin_amdgcn_mfma_f32_16x16x32_bf16(af, bf, acc[nf], 0, 0, 0);
            }
        }
        __syncthreads();   // protect Bs before next tile's copy
    }

    // ---- epilogue: bias (+ReLU), store fp32 ----
#pragma unroll
    for (int nf = 0; nf < NF; nf++) {
        int n = nf * 16 + m16;
        float b = bias[n];
#pragma unroll
        for (int r = 0; r < 4; r++) {
            int m = m0 + wave * 16 + q * 4 + r;
            if (m < M) {
                float v = acc[nf][r] + b;
                if (RELU) v = fmaxf(v, 0.0f);
                C[(size_t)m * BN + n] = v;
            }
        }
    }
}

// ---------------------------------------------------------------------------
extern "C" void kernel_launch(void* const* d_in, const int* in_sizes, int n_in,
                              void* d_out, int out_size, void* d_ws, size_t ws_size,
                              hipStream_t stream) {
    const float* x     = (const float*)d_in[0];
    const int*   ei    = (const int*)d_in[1];   // [2, NE]
    const int*   et    = (const int*)d_in[2];   // [NE]
    const float* W1    = (const float*)d_in[3]; // [4,128,128] == [512,128]
    const float* root1 = (const float*)d_in[4]; // [128,128]
    const float* b1    = (const float*)d_in[5];
    const float* W2    = (const float*)d_in[6]; // [4,128,96] == [512,96]
    const float* root2 = (const float*)d_in[7]; // [128,96]
    const float* b2    = (const float*)d_in[8];
    const int* srcp = ei;
    const int* dstp = ei + NE;
    float* out = (float*)d_out;

    // Workspace layout (floats)
    float* A   = (float*)d_ws;                    // NN*512
    float* h   = A   + (size_t)NN * KREL;         // NN*128
    float* cnt = h   + (size_t)NN * D;            // NN*4
    short* Wp1 = (short*)(cnt + (size_t)NN * NREL);       // 640*128 bf16
    short* Wp2 = Wp1 + (size_t)KCAT * D;                  // 640*96 bf16

    const int mblocks = (NN + 63) / 64;  // 1563

    // Shared preliminaries
    hipMemsetAsync(cnt, 0, (size_t)NN * NREL * sizeof(float), stream);
    count_deg<<<(NE + 255) / 256, 256, 0, stream>>>(dstp, et, cnt);
    pack_wcp<<<(KCAT * D + 255) / 256, 256, 0, stream>>>(W1, root1, Wp1, D);
    pack_wcp<<<(KCAT * DOUT2 + 255) / 256, 256, 0, stream>>>(W2, root2, Wp2, DOUT2);

    // ---- Layer 1: h = relu([A|x] @ Wc1 + b1) ----
    hipMemsetAsync(A, 0, (size_t)NN * KREL * sizeof(float), stream);
    scatter_edges<<<NE, D, 0, stream>>>(x, srcp, dstp, et, cnt, A);
    gemm_mfma<128, true><<<dim3(mblocks), 256, 0, stream>>>(A, x, Wp1, b1, h, NN);

    // ---- Layer 2: out = [A|h] @ Wc2 + b2 ----
    hipMemsetAsync(A, 0, (size_t)NN * KREL * sizeof(float), stream);
    scatter_edges<<<NE, D, 0, stream>>>(h, srcp, dstp, et, cnt, A);
    gemm_mfma<96, false><<<dim3(mblocks), 256, 0, stream>>>(A, h, Wp2, b2, out, NN);
}

// Round 3
// 633.066 us; speedup vs baseline: 2.6215x; 1.6023x over previous
//
#include <hip/hip_runtime.h>

// Problem constants
#define NN 100000      // nodes
#define NE 600000      // edges
#define D  128         // feature dim in (both layers)
#define DOUT2 96
#define NREL 4
#define KREL 512       // NREL * D
#define KCAT 640       // KREL + D
#define SCAN_B 98      // ceil(NN / 1024)

typedef short short8 __attribute__((ext_vector_type(8)));   // 8 bf16
typedef float f32x4  __attribute__((ext_vector_type(4)));

// fp32 -> bf16 round-to-nearest-even (finite inputs)
__device__ __forceinline__ short f2bf(float x) {
    unsigned u = __builtin_bit_cast(unsigned, x);
    u += 0x7fffu + ((u >> 16) & 1u);
    return (short)(u >> 16);
}

// ---------------------------------------------------------------------------
// cnt[v][r] = #edges with dst=v, etype=r (float atomics; counts exact)
__global__ void count_deg(const int* __restrict__ dst,
                          const int* __restrict__ et,
                          float* __restrict__ cnt) {
    int e = blockIdx.x * blockDim.x + threadIdx.x;
    if (e < NE) unsafeAtomicAdd(&cnt[dst[e] * NREL + et[e]], 1.0f);
}

// ---------------------------------------------------------------------------
// Prefix sum of per-node degree (deg[v] = sum_r cnt[v][r]) -> off[0..NN]
// 3-kernel scan: block sums -> scan of 98 sums -> emit.
__global__ void scan1(const float* __restrict__ cnt, int* __restrict__ bsum) {
    __shared__ int s[256];
    int tid = threadIdx.x;
    int base = blockIdx.x * 1024 + tid * 4;
    int t = 0;
    for (int i = 0; i < 4; i++) {
        int v = base + i;
        if (v < NN) {
            float4 c = *(const float4*)&cnt[(size_t)v * 4];
            t += (int)(c.x + c.y + c.z + c.w);
        }
    }
    s[tid] = t; __syncthreads();
    for (int o = 128; o > 0; o >>= 1) {
        if (tid < o) s[tid] += s[tid + o];
        __syncthreads();
    }
    if (tid == 0) bsum[blockIdx.x] = s[0];
}

__global__ void scan2(int* __restrict__ bsum) {  // 1 block of 128; in-place exclusive
    __shared__ int s[128];
    int tid = threadIdx.x;
    int mine = (tid < SCAN_B) ? bsum[tid] : 0;
    s[tid] = mine; __syncthreads();
    for (int o = 1; o < 128; o <<= 1) {
        int v = (tid >= o) ? s[tid - o] : 0;
        __syncthreads();
        s[tid] += v;
        __syncthreads();
    }
    if (tid < SCAN_B) bsum[tid] = s[tid] - mine;
}

__global__ void scan3(const float* __restrict__ cnt, const int* __restrict__ bsum,
                      int* __restrict__ off) {
    __shared__ int s[256];
    int tid = threadIdx.x;
    int base = blockIdx.x * 1024 + tid * 4;
    int d[4]; int t = 0;
    for (int i = 0; i < 4; i++) {
        int v = base + i; d[i] = 0;
        if (v < NN) {
            float4 c = *(const float4*)&cnt[(size_t)v * 4];
            d[i] = (int)(c.x + c.y + c.z + c.w);
        }
        t += d[i];
    }
    int mine = t;
    s[tid] = t; __syncthreads();
    for (int o = 1; o < 256; o <<= 1) {
        int v = (tid >= o) ? s[tid - o] : 0;
        __syncthreads();
        s[tid] += v;
        __syncthreads();
    }
    int ex = s[tid] - mine + bsum[blockIdx.x];
    for (int i = 0; i < 4; i++) {
        int v = base + i;
        if (v < NN) { off[v] = ex; ex += d[i]; }
    }
    if (blockIdx.x == 0 && tid == 0) off[NN] = NE;
}

// ---------------------------------------------------------------------------
// Bucket edges by dst; store packed (src<<2)|etype so the hot loop has one
// less indirection level.
__global__ void bucket_edges(const int* __restrict__ src, const int* __restrict__ dst,
                             const int* __restrict__ et, const int* __restrict__ off,
                             int* __restrict__ fill, int* __restrict__ srcpk) {
    int e = blockIdx.x * blockDim.x + threadIdx.x;
    if (e >= NE) return;
    int dn = dst[e];
    int pos = off[dn] + atomicAdd(&fill[dn], 1);
    srcpk[pos] = (src[e] << 2) | et[e];
}

// ---------------------------------------------------------------------------
// Pack Wcat = [W (512 x BN); root (128 x BN)] into bf16 MFMA-B-fragment order:
// Wcp[kq][n][j] = Wcat[kq*8+j][n], kq in [0,80), j in [0,8).
__global__ void pack_wcp(const float* __restrict__ W,
                         const float* __restrict__ root,
                         short* __restrict__ Wcp, int BN) {
    int i = blockIdx.x * blockDim.x + threadIdx.x;
    int total = KCAT * BN;
    if (i >= total) return;
    int j = i & 7;
    int rest = i >> 3;
    int n = rest % BN;
    int kq = rest / BN;
    int k = kq * 8 + j;
    float v = (k < KREL) ? W[(size_t)k * BN + n] : root[(size_t)(k - KREL) * BN + n];
    Wcp[i] = f2bf(v);
}

// ---------------------------------------------------------------------------
// Fused RGCN layer: per-wave, 16 dst nodes.
//   Phase 1: aggregate sum(norm * X[src]) per relation in fp32 registers
//            (lane l holds features 2l, 2l+1 for each of the 4 relations),
//            stage bf16 into wave-private LDS in MFMA A-fragment order.
//   Phase 2: 16x640 @ 640xBN MFMA GEMM; B-fragments direct from L2-resident
//            packed Wcp; k 512..640 ( root part ) read from X rows directly.
// No __syncthreads anywhere: LDS tile is wave-private (same-wave DS ordering).
template <int BN, bool RELU>
__global__ __launch_bounds__(128) void rgcn_fused(
    const float* __restrict__ X,     // [M,128]
    const int*   __restrict__ srcpk, // [NE] bucketed, packed (src<<2)|t
    const int*   __restrict__ off,   // [M+1]
    const float* __restrict__ cnt,   // [M,4]
    const short* __restrict__ Wcp,   // [80][BN][8] bf16
    const float* __restrict__ bias,  // [BN]
    float*       __restrict__ C,     // [M,BN]
    int M) {
    constexpr int NF = BN / 16;
    __shared__ short At[2][8192];    // 2 waves x (16 nodes x 512 feats) bf16, frag order

    const int tid  = threadIdx.x;
    const int wave = tid >> 6;
    const int lane = tid & 63;
    const int m16  = lane & 15;
    const int q    = lane >> 4;
    const int v0   = blockIdx.x * 32 + wave * 16;
    short* Aw = At[wave];

    // ---- phase 1: aggregate 16 nodes ----
    for (int nv = 0; nv < 16; nv++) {
        int v = v0 + nv;
        float2 a0 = {0.f,0.f}, a1 = {0.f,0.f}, a2 = {0.f,0.f}, a3 = {0.f,0.f};
        if (v < M) {
            float4 c4 = *(const float4*)&cnt[(size_t)v * 4];
            float n0 = 1.0f / fmaxf(c4.x, 1.0f);
            float n1 = 1.0f / fmaxf(c4.y, 1.0f);
            float n2 = 1.0f / fmaxf(c4.z, 1.0f);
            float n3 = 1.0f / fmaxf(c4.w, 1.0f);
            int e = off[v], end = off[v + 1];
#define ACCP(T, NRM, XV) {                                        \
            if      (T == 0) { a0.x += n0 * XV.x; a0.y += n0 * XV.y; } \
            else if (T == 1) { a1.x += n1 * XV.x; a1.y += n1 * XV.y; } \
            else if (T == 2) { a2.x += n2 * XV.x; a2.y += n2 * XV.y; } \
            else             { a3.x += n3 * XV.x; a3.y += n3 * XV.y; } }
            for (; e + 1 < end; e += 2) {   // 2 gathers in flight
                int p0 = __builtin_amdgcn_readfirstlane(srcpk[e]);
                int p1 = __builtin_amdgcn_readfirstlane(srcpk[e + 1]);
                float2 x0 = *(const float2*)&X[(size_t)(p0 >> 2) * D + 2 * lane];
                float2 x1 = *(const float2*)&X[(size_t)(p1 >> 2) * D + 2 * lane];
                int t0 = p0 & 3, t1 = p1 & 3;
                ACCP(t0, , x0);
                ACCP(t1, , x1);
            }
            if (e < end) {
                int p0 = __builtin_amdgcn_readfirstlane(srcpk[e]);
                float2 x0 = *(const float2*)&X[(size_t)(p0 >> 2) * D + 2 * lane];
                int t0 = p0 & 3;
                ACCP(t0, , x0);
            }
#undef ACCP
        }
        // write row nv in fragment order: feature pair (2l,2l+1), relation r:
        // short index = ((r*16 + (l>>2))*16 + nv)*8 + 2*(l&3)
        int b_ = (((lane >> 2) * 16) + nv) * 8 + 2 * (lane & 3);
        *(short2*)&Aw[b_       ] = make_short2(f2bf(a0.x), f2bf(a0.y));
        *(short2*)&Aw[b_ + 2048] = make_short2(f2bf(a1.x), f2bf(a1.y));
        *(short2*)&Aw[b_ + 4096] = make_short2(f2bf(a2.x), f2bf(a2.y));
        *(short2*)&Aw[b_ + 6144] = make_short2(f2bf(a3.x), f2bf(a3.y));
    }

    // ---- phase 2: 16x640 @ 640xBN GEMM ----
    f32x4 acc[NF];
#pragma unroll
    for (int i = 0; i < NF; i++) acc[i] = (f32x4)0.0f;

    // k = 0..511 from LDS tile
#pragma unroll 4
    for (int ks = 0; ks < 16; ks++) {
        short8 af = *(const short8*)&Aw[((ks * 4 + q) * 16 + m16) * 8];
        const short* bbase = Wcp + ((size_t)(ks * 4 + q) * BN + m16) * 8;
#pragma unroll
        for (int nf = 0; nf < NF; nf++) {
            short8 bf = *(const short8*)(bbase + nf * 128);
            acc[nf] = __builtin_amdgcn_mfma_f32_16x16x32_bf16(af, bf, acc[nf], 0, 0, 0);
        }
    }
    // k = 512..639 (root part) from X rows directly
    {
        int rowc = v0 + m16; if (rowc > M - 1) rowc = M - 1;
        const float* Xrow = X + (size_t)rowc * D;
#pragma unroll
        for (int s2 = 0; s2 < 4; s2++) {
            const float* p = Xrow + s2 * 32 + q * 8;
            float4 u0 = *(const float4*)p;
            float4 u1 = *(const float4*)(p + 4);
            short8 af;
            af[0] = f2bf(u0.x); af[1] = f2bf(u0.y);
            af[2] = f2bf(u0.z); af[3] = f2bf(u0.w);
            af[4] = f2bf(u1.x); af[5] = f2bf(u1.y);
            af[6] = f2bf(u1.z); af[7] = f2bf(u1.w);
            const short* bbase = Wcp + ((size_t)((16 + s2) * 4 + q) * BN + m16) * 8;
#pragma unroll
            for (int nf = 0; nf < NF; nf++) {
                short8 bf = *(const short8*)(bbase + nf * 128);
                acc[nf] = __builtin_amdgcn_mfma_f32_16x16x32_bf16(af, bf, acc[nf], 0, 0, 0);
            }
        }
    }

    // ---- epilogue ----
#pragma unroll
    for (int nf = 0; nf < NF; nf++) {
        int n = nf * 16 + m16;
        float b = bias[n];
#pragma unroll
        for (int r = 0; r < 4; r++) {
            int m = v0 + q * 4 + r;
            if (m < M) {
                float v = acc[nf][r] + b;
                if (RELU) v = fmaxf(v, 0.0f);
                C[(size_t)m * BN + n] = v;
            }
        }
    }
}

// ---------------------------------------------------------------------------
extern "C" void kernel_launch(void* const* d_in, const int* in_sizes, int n_in,
                              void* d_out, int out_size, void* d_ws, size_t ws_size,
                              hipStream_t stream) {
    const float* x     = (const float*)d_in[0];
    const int*   ei    = (const int*)d_in[1];
    const int*   et    = (const int*)d_in[2];
    const float* W1    = (const float*)d_in[3];
    const float* root1 = (const float*)d_in[4];
    const float* b1    = (const float*)d_in[5];
    const float* W2    = (const float*)d_in[6];
    const float* root2 = (const float*)d_in[7];
    const float* b2    = (const float*)d_in[8];
    const int* srcp = ei;
    const int* dstp = ei + NE;
    float* out = (float*)d_out;

    // Workspace layout
    float* h     = (float*)d_ws;                      // NN*128 f32
    float* cnt   = h + (size_t)NN * D;                // NN*4 f32
    int*   off   = (int*)(cnt + (size_t)NN * NREL);   // NN+1
    int*   fill  = off + (NN + 1);                    // NN
    int*   bsum  = fill + NN;                         // 128
    int*   srcpk = bsum + 128;                        // NE
    short* Wp1   = (short*)(srcpk + NE);              // 640*128 bf16
    short* Wp2   = Wp1 + (size_t)KCAT * D;            // 640*96 bf16

    // ---- build graph structures (once per launch; shared by both layers) ----
    hipMemsetAsync(cnt, 0, (size_t)NN * NREL * sizeof(float), stream);
    hipMemsetAsync(fill, 0, (size_t)NN * sizeof(int), stream);
    count_deg<<<(NE + 255) / 256, 256, 0, stream>>>(dstp, et, cnt);
    scan1<<<SCAN_B, 256, 0, stream>>>(cnt, bsum);
    scan2<<<1, 128, 0, stream>>>(bsum);
    scan3<<<SCAN_B, 256, 0, stream>>>(cnt, bsum, off);
    bucket_edges<<<(NE + 255) / 256, 256, 0, stream>>>(srcp, dstp, et, off, fill, srcpk);
    pack_wcp<<<(KCAT * D + 255) / 256, 256, 0, stream>>>(W1, root1, Wp1, D);
    pack_wcp<<<(KCAT * DOUT2 + 255) / 256, 256, 0, stream>>>(W2, root2, Wp2, DOUT2);

    const int fblocks = (NN + 31) / 32;  // 3125

    // ---- Layer 1: h = relu(agg(x) @ W1cat + b1) ----
    rgcn_fused<128, true><<<fblocks, 128, 0, stream>>>(x, srcpk, off, cnt, Wp1, b1, h, NN);
    // ---- Layer 2: out = agg(h) @ W2cat + b2 ----
    rgcn_fused<96, false><<<fblocks, 128, 0, stream>>>(h, srcpk, off, cnt, Wp2, b2, out, NN);
}

// Round 4
// 444.876 us; speedup vs baseline: 3.7305x; 1.4230x over previous
//
#include <hip/hip_runtime.h>

// Problem constants
#define NN 100000      // nodes
#define NE 600000      // edges
#define D  128         // feature dim in (both layers)
#define DOUT2 96
#define NREL 4
#define KREL 512       // NREL * D
#define KCAT 640       // KREL + D
#define SCAN_B 98      // ceil(NN / 1024)

typedef short short8 __attribute__((ext_vector_type(8)));   // 8 bf16
typedef float f32x4  __attribute__((ext_vector_type(4)));

// fp32 -> bf16 round-to-nearest-even (finite inputs)
__device__ __forceinline__ ushort f2bf(float x) {
    unsigned u = __builtin_bit_cast(unsigned, x);
    u += 0x7fffu + ((u >> 16) & 1u);
    return (ushort)(u >> 16);
}
__device__ __forceinline__ float bfhi(unsigned u) {  // high bf16 of packed pair
    return __builtin_bit_cast(float, u & 0xffff0000u);
}
__device__ __forceinline__ float bflo(unsigned u) {  // low bf16 of packed pair
    return __builtin_bit_cast(float, u << 16);
}

// ---------------------------------------------------------------------------
// x (fp32) -> bf16
__global__ void cvt_bf16(const float* __restrict__ x, ushort* __restrict__ xb) {
    int i = (blockIdx.x * 256 + threadIdx.x) * 4;
    float4 v = *(const float4*)&x[i];
    ushort4 o;
    o.x = f2bf(v.x); o.y = f2bf(v.y); o.z = f2bf(v.z); o.w = f2bf(v.w);
    *(ushort4*)&xb[i] = o;
}

// ---------------------------------------------------------------------------
// cnt[v][r] = #edges with dst=v, etype=r
__global__ void count_deg(const int* __restrict__ dst,
                          const int* __restrict__ et,
                          float* __restrict__ cnt) {
    int e = blockIdx.x * blockDim.x + threadIdx.x;
    if (e < NE) unsafeAtomicAdd(&cnt[dst[e] * NREL + et[e]], 1.0f);
}

// ---------------------------------------------------------------------------
// Prefix sum of per-node degree -> off[0..NN] (3-kernel scan)
__global__ void scan1(const float* __restrict__ cnt, int* __restrict__ bsum) {
    __shared__ int s[256];
    int tid = threadIdx.x;
    int base = blockIdx.x * 1024 + tid * 4;
    int t = 0;
    for (int i = 0; i < 4; i++) {
        int v = base + i;
        if (v < NN) {
            float4 c = *(const float4*)&cnt[(size_t)v * 4];
            t += (int)(c.x + c.y + c.z + c.w);
        }
    }
    s[tid] = t; __syncthreads();
    for (int o = 128; o > 0; o >>= 1) {
        if (tid < o) s[tid] += s[tid + o];
        __syncthreads();
    }
    if (tid == 0) bsum[blockIdx.x] = s[0];
}

__global__ void scan2(int* __restrict__ bsum) {  // 1 block of 128; exclusive in-place
    __shared__ int s[128];
    int tid = threadIdx.x;
    int mine = (tid < SCAN_B) ? bsum[tid] : 0;
    s[tid] = mine; __syncthreads();
    for (int o = 1; o < 128; o <<= 1) {
        int v = (tid >= o) ? s[tid - o] : 0;
        __syncthreads();
        s[tid] += v;
        __syncthreads();
    }
    if (tid < SCAN_B) bsum[tid] = s[tid] - mine;
}

__global__ void scan3(const float* __restrict__ cnt, const int* __restrict__ bsum,
                      int* __restrict__ off) {
    __shared__ int s[256];
    int tid = threadIdx.x;
    int base = blockIdx.x * 1024 + tid * 4;
    int d[4]; int t = 0;
    for (int i = 0; i < 4; i++) {
        int v = base + i; d[i] = 0;
        if (v < NN) {
            float4 c = *(const float4*)&cnt[(size_t)v * 4];
            d[i] = (int)(c.x + c.y + c.z + c.w);
        }
        t += d[i];
    }
    int mine = t;
    s[tid] = t; __syncthreads();
    for (int o = 1; o < 256; o <<= 1) {
        int v = (tid >= o) ? s[tid - o] : 0;
        __syncthreads();
        s[tid] += v;
        __syncthreads();
    }
    int ex = s[tid] - mine + bsum[blockIdx.x];
    for (int i = 0; i < 4; i++) {
        int v = base + i;
        if (v < NN) { off[v] = ex; ex += d[i]; }
    }
    if (blockIdx.x == 0 && tid == 0) off[NN] = NE;
}

// ---------------------------------------------------------------------------
// Bucket edges by dst; packed (src<<2)|etype
__global__ void bucket_edges(const int* __restrict__ src, const int* __restrict__ dst,
                             const int* __restrict__ et, const int* __restrict__ off,
                             int* __restrict__ fill, int* __restrict__ srcpk) {
    int e = blockIdx.x * blockDim.x + threadIdx.x;
    if (e >= NE) return;
    int dn = dst[e];
    int pos = off[dn] + atomicAdd(&fill[dn], 1);
    srcpk[pos] = (src[e] << 2) | et[e];
}

// ---------------------------------------------------------------------------
// Pack Wcat = [W (512 x BN); root (128 x BN)] into bf16 MFMA-B-fragment order:
// Wcp[kq][n][j] = Wcat[kq*8+j][n], kq in [0,80), j in [0,8).
__global__ void pack_wcp(const float* __restrict__ W,
                         const float* __restrict__ root,
                         short* __restrict__ Wcp, int BN) {
    int i = blockIdx.x * blockDim.x + threadIdx.x;
    int total = KCAT * BN;
    if (i >= total) return;
    int j = i & 7;
    int rest = i >> 3;
    int n = rest % BN;
    int kq = rest / BN;
    int k = kq * 8 + j;
    float v = (k < KREL) ? W[(size_t)k * BN + n] : root[(size_t)(k - KREL) * BN + n];
    Wcp[i] = (short)f2bf(v);
}

// ---------------------------------------------------------------------------
// Fused RGCN layer. Per wave: 16 dst nodes.
//   Phase 1 (quarter-wave per node, 4 rounds of 4 nodes): lanes l=0..15 of
//   quarter qw hold feats [8l,8l+8) of node (rho*4+qw); edges iterated with
//   4-edge unroll -> up to 16 independent bf16 row-gathers in flight/wave.
//   Accumulate fp32 with predicated per-relation scales (no divergence).
//   Stage bf16 A-tile in wave-private LDS in MFMA A-frag order (no barriers).
//   Phase 2: 16x640 @ 640xBN MFMA; B-frags from L2-resident packed Wcp;
//   root part (k>=512) read directly from the bf16 feature rows.
template <int BN, bool RELU, bool OUT_BF16>
__global__ __launch_bounds__(128) void rgcn_fused(
    const ushort* __restrict__ Xb,   // [M,128] bf16
    const int*   __restrict__ srcpk, // [NE] bucketed, (src<<2)|t
    const int*   __restrict__ off,   // [M+1]
    const float* __restrict__ cnt,   // [M,4]
    const short* __restrict__ Wcp,   // [80][BN][8] bf16
    const float* __restrict__ bias,  // [BN]
    void*        __restrict__ Cout,  // [M,BN] bf16 or f32
    int M) {
    constexpr int NF = BN / 16;
    __shared__ short At[2][64 * 128];   // per-wave 16 KB: [kq16][node][8]

    const int tid  = threadIdx.x;
    const int wave = tid >> 6;
    const int lane = tid & 63;
    const int l    = lane & 15;         // phase1: feat group / phase2: m16
    const int qw   = lane >> 4;         // phase1: quarter / phase2: k-quad q
    const int v0   = blockIdx.x * 32 + wave * 16;
    short* Aw = At[wave];

    // ---- phase 1: aggregate 16 nodes, 4 per round ----
    for (int rho = 0; rho < 4; rho++) {
        int nv = rho * 4 + qw;
        int v  = v0 + nv;
        float acc[4][8];
#pragma unroll
        for (int r = 0; r < 4; r++)
#pragma unroll
            for (int j = 0; j < 8; j++) acc[r][j] = 0.0f;

        if (v < M) {
            float4 c4 = *(const float4*)&cnt[(size_t)v * 4];
            float nrm0 = 1.0f / fmaxf(c4.x, 1.0f);
            float nrm1 = 1.0f / fmaxf(c4.y, 1.0f);
            float nrm2 = 1.0f / fmaxf(c4.z, 1.0f);
            float nrm3 = 1.0f / fmaxf(c4.w, 1.0f);
            int e = off[v], end = off[v + 1];

#define EDGE_ACC(PK, XB) {                                                  \
            int t_ = (PK) & 3;                                              \
            float s0 = (t_ == 0) ? nrm0 : 0.0f;                             \
            float s1 = (t_ == 1) ? nrm1 : 0.0f;                             \
            float s2 = (t_ == 2) ? nrm2 : 0.0f;                             \
            float s3 = (t_ == 3) ? nrm3 : 0.0f;                             \
            float xf[8];                                                    \
            xf[0] = bflo(XB.x); xf[1] = bfhi(XB.x);                         \
            xf[2] = bflo(XB.y); xf[3] = bfhi(XB.y);                         \
            xf[4] = bflo(XB.z); xf[5] = bfhi(XB.z);                         \
            xf[6] = bflo(XB.w); xf[7] = bfhi(XB.w);                         \
            _Pragma("unroll")                                               \
            for (int j = 0; j < 8; j++) {                                   \
                acc[0][j] += s0 * xf[j];                                    \
                acc[1][j] += s1 * xf[j];                                    \
                acc[2][j] += s2 * xf[j];                                    \
                acc[3][j] += s3 * xf[j];                                    \
            } }

            for (; e + 3 < end; e += 4) {   // 4 gathers in flight per quarter
                int p0 = srcpk[e],     p1 = srcpk[e + 1];
                int p2 = srcpk[e + 2], p3 = srcpk[e + 3];
                uint4 x0 = *(const uint4*)&Xb[(size_t)(p0 >> 2) * D + l * 8];
                uint4 x1 = *(const uint4*)&Xb[(size_t)(p1 >> 2) * D + l * 8];
                uint4 x2 = *(const uint4*)&Xb[(size_t)(p2 >> 2) * D + l * 8];
                uint4 x3 = *(const uint4*)&Xb[(size_t)(p3 >> 2) * D + l * 8];
                EDGE_ACC(p0, x0); EDGE_ACC(p1, x1);
                EDGE_ACC(p2, x2); EDGE_ACC(p3, x3);
            }
            for (; e < end; e++) {
                int p0 = srcpk[e];
                uint4 x0 = *(const uint4*)&Xb[(size_t)(p0 >> 2) * D + l * 8];
                EDGE_ACC(p0, x0);
            }
#undef EDGE_ACC
        }

        // stage to LDS in A-frag order: row kq16 = r*16 + l, node nv, 8 bf16
#pragma unroll
        for (int r = 0; r < 4; r++) {
            short8 w;
#pragma unroll
            for (int j = 0; j < 8; j++) w[j] = (short)f2bf(acc[r][j]);
            *(short8*)&Aw[((r * 16 + l) * 16 + nv) * 8] = w;
        }
    }

    // ---- phase 2: 16x640 @ 640xBN MFMA GEMM ----
    const int m16 = l;
    const int q   = qw;
    f32x4 acc2[NF];
#pragma unroll
    for (int i = 0; i < NF; i++) acc2[i] = (f32x4)0.0f;

#pragma unroll 4
    for (int ks = 0; ks < 16; ks++) {
        short8 af = *(const short8*)&Aw[((ks * 4 + q) * 16 + m16) * 8];
        const short* bbase = Wcp + ((size_t)(ks * 4 + q) * BN + m16) * 8;
#pragma unroll
        for (int nf = 0; nf < NF; nf++) {
            short8 bf = *(const short8*)(bbase + nf * 128);
            acc2[nf] = __builtin_amdgcn_mfma_f32_16x16x32_bf16(af, bf, acc2[nf], 0, 0, 0);
        }
    }
    {   // root part: k = 512..639 directly from bf16 feature rows
        int rowc = v0 + m16; if (rowc > M - 1) rowc = M - 1;
        const ushort* Xrow = Xb + (size_t)rowc * D;
#pragma unroll
        for (int s2 = 0; s2 < 4; s2++) {
            short8 af = *(const short8*)&Xrow[s2 * 32 + q * 8];
            const short* bbase = Wcp + ((size_t)((16 + s2) * 4 + q) * BN + m16) * 8;
#pragma unroll
            for (int nf = 0; nf < NF; nf++) {
                short8 bf = *(const short8*)(bbase + nf * 128);
                acc2[nf] = __builtin_amdgcn_mfma_f32_16x16x32_bf16(af, bf, acc2[nf], 0, 0, 0);
            }
        }
    }

    // ---- epilogue ----
#pragma unroll
    for (int nf = 0; nf < NF; nf++) {
        int n = nf * 16 + m16;
        float b = bias[n];
#pragma unroll
        for (int r = 0; r < 4; r++) {
            int m = v0 + q * 4 + r;
            if (m < M) {
                float vv = acc2[nf][r] + b;
                if (RELU) vv = fmaxf(vv, 0.0f);
                if (OUT_BF16) ((ushort*)Cout)[(size_t)m * BN + n] = f2bf(vv);
                else          ((float*)Cout)[(size_t)m * BN + n]  = vv;
            }
        }
    }
}

// ---------------------------------------------------------------------------
extern "C" void kernel_launch(void* const* d_in, const int* in_sizes, int n_in,
                              void* d_out, int out_size, void* d_ws, size_t ws_size,
                              hipStream_t stream) {
    const float* x     = (const float*)d_in[0];
    const int*   ei    = (const int*)d_in[1];
    const int*   et    = (const int*)d_in[2];
    const float* W1    = (const float*)d_in[3];
    const float* root1 = (const float*)d_in[4];
    const float* b1    = (const float*)d_in[5];
    const float* W2    = (const float*)d_in[6];
    const float* root2 = (const float*)d_in[7];
    const float* b2    = (const float*)d_in[8];
    const int* srcp = ei;
    const int* dstp = ei + NE;
    float* out = (float*)d_out;

    // Workspace layout (all segments 16-B aligned: sizes are multiples of 16 B)
    short*  Wp1  = (short*)d_ws;                        // 640*128 bf16 = 163840 B
    short*  Wp2  = Wp1 + (size_t)KCAT * D;              // 640*96  bf16 = 122880 B
    ushort* Xb   = (ushort*)(Wp2 + (size_t)KCAT * DOUT2); // NN*128 bf16 = 25.6 MB
    ushort* h    = Xb + (size_t)NN * D;                 // NN*128 bf16 = 25.6 MB
    float*  cnt  = (float*)(h + (size_t)NN * D);        // NN*4 f32 = 1.6 MB
    int*    off  = (int*)(cnt + (size_t)NN * NREL);     // NN+1
    int*    fill = off + (NN + 1);                      // NN
    int*    bsum = fill + NN;                           // 128
    int*    srcpk= bsum + 128;                          // NE

    // ---- prep (shared by both layers) ----
    hipMemsetAsync(cnt, 0, (size_t)NN * NREL * sizeof(float), stream);
    hipMemsetAsync(fill, 0, (size_t)NN * sizeof(int), stream);
    cvt_bf16<<<(NN * D) / 1024, 256, 0, stream>>>(x, Xb);
    count_deg<<<(NE + 255) / 256, 256, 0, stream>>>(dstp, et, cnt);
    scan1<<<SCAN_B, 256, 0, stream>>>(cnt, bsum);
    scan2<<<1, 128, 0, stream>>>(bsum);
    scan3<<<SCAN_B, 256, 0, stream>>>(cnt, bsum, off);
    bucket_edges<<<(NE + 255) / 256, 256, 0, stream>>>(srcp, dstp, et, off, fill, srcpk);
    pack_wcp<<<(KCAT * D + 255) / 256, 256, 0, stream>>>(W1, root1, Wp1, D);
    pack_wcp<<<(KCAT * DOUT2 + 255) / 256, 256, 0, stream>>>(W2, root2, Wp2, DOUT2);

    const int fblocks = (NN + 31) / 32;  // 3125

    // ---- Layer 1: h = relu(agg(x) @ W1cat + b1), bf16 out ----
    rgcn_fused<128, true, true><<<fblocks, 128, 0, stream>>>(
        Xb, srcpk, off, cnt, Wp1, b1, h, NN);
    // ---- Layer 2: out = agg(h) @ W2cat + b2, f32 out ----
    rgcn_fused<96, false, false><<<fblocks, 128, 0, stream>>>(
        h, srcpk, off, cnt, Wp2, b2, out, NN);
}

// Round 5
// 325.696 us; speedup vs baseline: 5.0956x; 1.3659x over previous
//
#include <hip/hip_runtime.h>

// Problem constants
#define NN 100000      // nodes
#define NE 600000      // edges
#define D  128         // feature dim in (both layers)
#define DOUT2 96
#define NREL 4
#define KREL 512       // NREL * D
#define KCAT 640       // KREL + D
#define SCAN_B 98      // ceil(NN / 1024)

typedef short short8 __attribute__((ext_vector_type(8)));   // 8 bf16
typedef float f32x4  __attribute__((ext_vector_type(4)));

// fp32 -> bf16 round-to-nearest-even (finite inputs)
__device__ __forceinline__ ushort f2bf(float x) {
    unsigned u = __builtin_bit_cast(unsigned, x);
    u += 0x7fffu + ((u >> 16) & 1u);
    return (ushort)(u >> 16);
}
__device__ __forceinline__ float bfhi(unsigned u) {
    return __builtin_bit_cast(float, u & 0xffff0000u);
}
__device__ __forceinline__ float bflo(unsigned u) {
    return __builtin_bit_cast(float, u << 16);
}

// ---------------------------------------------------------------------------
// Fused independent prep: zero cnt, zero fill, x->bf16, pack Wcp1, pack Wcp2.
// One dispatch instead of five (graph capture serializes the stream).
__global__ void prep0(const float* __restrict__ x, ushort* __restrict__ Xb,
                      const float* __restrict__ W1, const float* __restrict__ root1,
                      short* __restrict__ Wp1,
                      const float* __restrict__ W2, const float* __restrict__ root2,
                      short* __restrict__ Wp2,
                      float* __restrict__ cnt, int* __restrict__ fill) {
    int i = blockIdx.x * 256 + threadIdx.x;
    const int S0 = (NN * NREL) / 4;   // 100000 float4 zeros of cnt
    const int S1 = NN / 4;            // 25000 int4 zeros of fill
    const int S2 = (NN * D) / 4;      // 3200000 float4->ushort4 converts
    const int S3 = KCAT * D;          // 81920 pack1 elements
    const int S4 = KCAT * DOUT2;      // 61440 pack2 elements
    if (i < S0) { ((float4*)cnt)[i] = make_float4(0.f, 0.f, 0.f, 0.f); return; }
    i -= S0;
    if (i < S1) { ((int4*)fill)[i] = make_int4(0, 0, 0, 0); return; }
    i -= S1;
    if (i < S2) {
        float4 v = ((const float4*)x)[i];
        ushort4 o;
        o.x = f2bf(v.x); o.y = f2bf(v.y); o.z = f2bf(v.z); o.w = f2bf(v.w);
        ((ushort4*)Xb)[i] = o;
        return;
    }
    i -= S2;
    if (i < S3) {   // Wcp[kq][n][j] = Wcat[kq*8+j][n], BN = 128
        int j = i & 7, rest = i >> 3;
        int n = rest % D, kq = rest / D;
        int k = kq * 8 + j;
        float v = (k < KREL) ? W1[(size_t)k * D + n] : root1[(size_t)(k - KREL) * D + n];
        Wp1[i] = (short)f2bf(v);
        return;
    }
    i -= S3;
    if (i < S4) {   // BN = 96
        int j = i & 7, rest = i >> 3;
        int n = rest % DOUT2, kq = rest / DOUT2;
        int k = kq * 8 + j;
        float v = (k < KREL) ? W2[(size_t)k * DOUT2 + n] : root2[(size_t)(k - KREL) * DOUT2 + n];
        Wp2[i] = (short)f2bf(v);
        return;
    }
}

// ---------------------------------------------------------------------------
// cnt[v][r] = #edges with dst=v, etype=r
__global__ void count_deg(const int* __restrict__ dst,
                          const int* __restrict__ et,
                          float* __restrict__ cnt) {
    int e = blockIdx.x * blockDim.x + threadIdx.x;
    if (e < NE) unsafeAtomicAdd(&cnt[dst[e] * NREL + et[e]], 1.0f);
}

// ---------------------------------------------------------------------------
// Prefix sum of per-node degree -> off[0..NN] (3-kernel scan)
__global__ void scan1(const float* __restrict__ cnt, int* __restrict__ bsum) {
    __shared__ int s[256];
    int tid = threadIdx.x;
    int base = blockIdx.x * 1024 + tid * 4;
    int t = 0;
    for (int i = 0; i < 4; i++) {
        int v = base + i;
        if (v < NN) {
            float4 c = *(const float4*)&cnt[(size_t)v * 4];
            t += (int)(c.x + c.y + c.z + c.w);
        }
    }
    s[tid] = t; __syncthreads();
    for (int o = 128; o > 0; o >>= 1) {
        if (tid < o) s[tid] += s[tid + o];
        __syncthreads();
    }
    if (tid == 0) bsum[blockIdx.x] = s[0];
}

__global__ void scan2(int* __restrict__ bsum) {  // 1 block of 128; exclusive in-place
    __shared__ int s[128];
    int tid = threadIdx.x;
    int mine = (tid < SCAN_B) ? bsum[tid] : 0;
    s[tid] = mine; __syncthreads();
    for (int o = 1; o < 128; o <<= 1) {
        int v = (tid >= o) ? s[tid - o] : 0;
        __syncthreads();
        s[tid] += v;
        __syncthreads();
    }
    if (tid < SCAN_B) bsum[tid] = s[tid] - mine;
}

__global__ void scan3(const float* __restrict__ cnt, const int* __restrict__ bsum,
                      int* __restrict__ off) {
    __shared__ int s[256];
    int tid = threadIdx.x;
    int base = blockIdx.x * 1024 + tid * 4;
    int d[4]; int t = 0;
    for (int i = 0; i < 4; i++) {
        int v = base + i; d[i] = 0;
        if (v < NN) {
            float4 c = *(const float4*)&cnt[(size_t)v * 4];
            d[i] = (int)(c.x + c.y + c.z + c.w);
        }
        t += d[i];
    }
    int mine = t;
    s[tid] = t; __syncthreads();
    for (int o = 1; o < 256; o <<= 1) {
        int v = (tid >= o) ? s[tid - o] : 0;
        __syncthreads();
        s[tid] += v;
        __syncthreads();
    }
    int ex = s[tid] - mine + bsum[blockIdx.x];
    for (int i = 0; i < 4; i++) {
        int v = base + i;
        if (v < NN) { off[v] = ex; ex += d[i]; }
    }
    if (blockIdx.x == 0 && tid == 0) off[NN] = NE;
}

// ---------------------------------------------------------------------------
// Bucket edges by dst; packed (src<<2)|etype
__global__ void bucket_edges(const int* __restrict__ src, const int* __restrict__ dst,
                             const int* __restrict__ et, const int* __restrict__ off,
                             int* __restrict__ fill, int* __restrict__ srcpk) {
    int e = blockIdx.x * blockDim.x + threadIdx.x;
    if (e >= NE) return;
    int dn = dst[e];
    int pos = off[dn] + atomicAdd(&fill[dn], 1);
    srcpk[pos] = (src[e] << 2) | et[e];
}

// ---------------------------------------------------------------------------
// Fused RGCN layer — block-shared A-tile version.
// Block = 256 threads (4 waves), 32 dst nodes, one 32 KB LDS tile
// [kq16=64][node=32][8 bf16] (MFMA A-frag order). 5 blocks/CU.
//   Phase 1: 16 quarter-wave chains; chain g aggregates nodes v0+g, v0+g+16
//            (full per-node edge range, 4-edge unrolled gathers, fp32 acc
//            with predicated per-relation scales).
//   Phase 2 (after one barrier): wave w computes quadrant
//            (m-half = w&1, n-half = w>>1): 16 nodes x NFW*16 cols.
//            B-frags direct from L2-resident packed Wcp; root part (k>=512)
//            read from the bf16 feature rows.
template <int BN, bool RELU, bool OUT_BF16>
__global__ __launch_bounds__(256, 5) void rgcn_fused(
    const ushort* __restrict__ Xb,   // [M,128] bf16
    const int*   __restrict__ srcpk, // [NE] bucketed, (src<<2)|t
    const int*   __restrict__ off,   // [M+1]
    const float* __restrict__ cnt,   // [M,4]
    const short* __restrict__ Wcp,   // [80][BN][8] bf16
    const float* __restrict__ bias,  // [BN]
    void*        __restrict__ Cout,  // [M,BN] bf16 or f32
    int M) {
    constexpr int NFW = (BN / 16 + 1) / 2;   // frags per wave: 4 (BN=128) / 3 (BN=96)
    __shared__ short At[64 * 32 * 8];        // 32 KB

    const int tid  = threadIdx.x;
    const int wave = tid >> 6;
    const int lane = tid & 63;
    const int l    = lane & 15;     // phase1: feat group / phase2: m16
    const int qw   = lane >> 4;     // phase1: quarter / phase2: k-quad q
    const int g    = wave * 4 + qw; // chain id 0..15
    const int v0   = blockIdx.x * 32;

    // ---- phase 1: aggregate 32 nodes (2 per chain) ----
#pragma unroll
    for (int half = 0; half < 2; half++) {
        int nv = g + half * 16;
        int v  = v0 + nv;           // NN % 32 == 0 -> always < M
        float acc[4][8];
#pragma unroll
        for (int r = 0; r < 4; r++)
#pragma unroll
            for (int j = 0; j < 8; j++) acc[r][j] = 0.0f;

        float4 c4 = *(const float4*)&cnt[(size_t)v * 4];
        float nrm0 = 1.0f / fmaxf(c4.x, 1.0f);
        float nrm1 = 1.0f / fmaxf(c4.y, 1.0f);
        float nrm2 = 1.0f / fmaxf(c4.z, 1.0f);
        float nrm3 = 1.0f / fmaxf(c4.w, 1.0f);
        int e = off[v], end = off[v + 1];

#define EDGE_ACC(PK, XB) {                                                  \
        int t_ = (PK) & 3;                                                  \
        float s0 = (t_ == 0) ? nrm0 : 0.0f;                                 \
        float s1 = (t_ == 1) ? nrm1 : 0.0f;                                 \
        float s2 = (t_ == 2) ? nrm2 : 0.0f;                                 \
        float s3 = (t_ == 3) ? nrm3 : 0.0f;                                 \
        float xf[8];                                                        \
        xf[0] = bflo(XB.x); xf[1] = bfhi(XB.x);                             \
        xf[2] = bflo(XB.y); xf[3] = bfhi(XB.y);                             \
        xf[4] = bflo(XB.z); xf[5] = bfhi(XB.z);                             \
        xf[6] = bflo(XB.w); xf[7] = bfhi(XB.w);                             \
        _Pragma("unroll")                                                   \
        for (int j = 0; j < 8; j++) {                                       \
            acc[0][j] += s0 * xf[j];                                        \
            acc[1][j] += s1 * xf[j];                                        \
            acc[2][j] += s2 * xf[j];                                        \
            acc[3][j] += s3 * xf[j];                                        \
        } }

        for (; e + 3 < end; e += 4) {   // 4 gathers in flight per chain
            int p0 = srcpk[e],     p1 = srcpk[e + 1];
            int p2 = srcpk[e + 2], p3 = srcpk[e + 3];
            uint4 x0 = *(const uint4*)&Xb[(size_t)(p0 >> 2) * D + l * 8];
            uint4 x1 = *(const uint4*)&Xb[(size_t)(p1 >> 2) * D + l * 8];
            uint4 x2 = *(const uint4*)&Xb[(size_t)(p2 >> 2) * D + l * 8];
            uint4 x3 = *(const uint4*)&Xb[(size_t)(p3 >> 2) * D + l * 8];
            EDGE_ACC(p0, x0); EDGE_ACC(p1, x1);
            EDGE_ACC(p2, x2); EDGE_ACC(p3, x3);
        }
        for (; e < end; e++) {
            int p0 = srcpk[e];
            uint4 x0 = *(const uint4*)&Xb[(size_t)(p0 >> 2) * D + l * 8];
            EDGE_ACC(p0, x0);
        }
#undef EDGE_ACC

        // stage to LDS in A-frag order: kq16 = r*16 + l, node nv
#pragma unroll
        for (int r = 0; r < 4; r++) {
            short8 w;
#pragma unroll
            for (int j = 0; j < 8; j++) w[j] = (short)f2bf(acc[r][j]);
            *(short8*)&At[((r * 16 + l) * 32 + nv) * 8] = w;
        }
    }

    __syncthreads();

    // ---- phase 2: 32x640 @ 640xBN, one quadrant per wave ----
    const int m16   = l;
    const int q     = qw;
    const int mt    = wave & 1;           // m-half (16 nodes)
    const int nbase = (wave >> 1) * NFW * 16;   // n-offset
    f32x4 acc2[NFW];
#pragma unroll
    for (int i = 0; i < NFW; i++) acc2[i] = (f32x4)0.0f;

#pragma unroll 4
    for (int ks = 0; ks < 16; ks++) {
        short8 af = *(const short8*)&At[((ks * 4 + q) * 32 + mt * 16 + m16) * 8];
        const short* bbase = Wcp + ((size_t)(ks * 4 + q) * BN + nbase + m16) * 8;
#pragma unroll
        for (int nf = 0; nf < NFW; nf++) {
            short8 bf = *(const short8*)(bbase + nf * 128);
            acc2[nf] = __builtin_amdgcn_mfma_f32_16x16x32_bf16(af, bf, acc2[nf], 0, 0, 0);
        }
    }
    {   // root part: k = 512..639 directly from bf16 feature rows
        int rowc = v0 + mt * 16 + m16;
        const ushort* Xrow = Xb + (size_t)rowc * D;
#pragma unroll
        for (int s2 = 0; s2 < 4; s2++) {
            short8 af = *(const short8*)&Xrow[s2 * 32 + q * 8];
            const short* bbase = Wcp + ((size_t)((16 + s2) * 4 + q) * BN + nbase + m16) * 8;
#pragma unroll
            for (int nf = 0; nf < NFW; nf++) {
                short8 bf = *(const short8*)(bbase + nf * 128);
                acc2[nf] = __builtin_amdgcn_mfma_f32_16x16x32_bf16(af, bf, acc2[nf], 0, 0, 0);
            }
        }
    }

    // ---- epilogue ----
#pragma unroll
    for (int nf = 0; nf < NFW; nf++) {
        int n = nbase + nf * 16 + m16;
        float b = bias[n];
#pragma unroll
        for (int r = 0; r < 4; r++) {
            int m = v0 + mt * 16 + q * 4 + r;
            float vv = acc2[nf][r] + b;
            if (RELU) vv = fmaxf(vv, 0.0f);
            if (OUT_BF16) ((ushort*)Cout)[(size_t)m * BN + n] = f2bf(vv);
            else          ((float*)Cout)[(size_t)m * BN + n]  = vv;
        }
    }
}

// ---------------------------------------------------------------------------
extern "C" void kernel_launch(void* const* d_in, const int* in_sizes, int n_in,
                              void* d_out, int out_size, void* d_ws, size_t ws_size,
                              hipStream_t stream) {
    const float* x     = (const float*)d_in[0];
    const int*   ei    = (const int*)d_in[1];
    const int*   et    = (const int*)d_in[2];
    const float* W1    = (const float*)d_in[3];
    const float* root1 = (const float*)d_in[4];
    const float* b1    = (const float*)d_in[5];
    const float* W2    = (const float*)d_in[6];
    const float* root2 = (const float*)d_in[7];
    const float* b2    = (const float*)d_in[8];
    const int* srcp = ei;
    const int* dstp = ei + NE;
    float* out = (float*)d_out;

    // Workspace layout (all segments 16-B aligned)
    short*  Wp1  = (short*)d_ws;                          // 640*128 bf16
    short*  Wp2  = Wp1 + (size_t)KCAT * D;                // 640*96  bf16
    ushort* Xb   = (ushort*)(Wp2 + (size_t)KCAT * DOUT2); // NN*128 bf16
    ushort* h    = Xb + (size_t)NN * D;                   // NN*128 bf16
    float*  cnt  = (float*)(h + (size_t)NN * D);          // NN*4 f32
    int*    off  = (int*)(cnt + (size_t)NN * NREL);       // NN+1
    int*    fill = off + (NN + 1);                        // NN
    int*    bsum = fill + NN;                             // 128
    int*    srcpk= bsum + 128;                            // NE

    // ---- prep (shared by both layers) ----
    {
        const int S = (NN * NREL) / 4 + NN / 4 + (NN * D) / 4 + KCAT * D + KCAT * DOUT2;
        prep0<<<(S + 255) / 256, 256, 0, stream>>>(x, Xb, W1, root1, Wp1,
                                                   W2, root2, Wp2, cnt, fill);
    }
    count_deg<<<(NE + 255) / 256, 256, 0, stream>>>(dstp, et, cnt);
    scan1<<<SCAN_B, 256, 0, stream>>>(cnt, bsum);
    scan2<<<1, 128, 0, stream>>>(bsum);
    scan3<<<SCAN_B, 256, 0, stream>>>(cnt, bsum, off);
    bucket_edges<<<(NE + 255) / 256, 256, 0, stream>>>(srcp, dstp, et, off, fill, srcpk);

    const int fblocks = NN / 32;  // 3125 (exact)

    // ---- Layer 1: h = relu(agg(x) @ W1cat + b1), bf16 out ----
    rgcn_fused<128, true, true><<<fblocks, 256, 0, stream>>>(
        Xb, srcpk, off, cnt, Wp1, b1, h, NN);
    // ---- Layer 2: out = agg(h) @ W2cat + b2, f32 out ----
    rgcn_fused<96, false, false><<<fblocks, 256, 0, stream>>>(
        h, srcpk, off, cnt, Wp2, b2, out, NN);
}